// Round 13
// baseline (152.208 us; speedup 1.0000x reference)
//
#include <hip/hip_runtime.h>
#include <math.h>

#define NTHR 256
#define MAXBLK 4096
#define PTS_PAD 20480   // bytes per SoA array slot (>= 5000*4, 16B-aligned)
#define REPS 4

// ws layout: [0, MAXBLK*8) double partials;
//            [32768 .. +4*PTS_PAD) SoA arrays x,y,vx,vy (float each);
//            [32768+4*PTS_PAD ...) float4 pts (AoS, for event gathers)

typedef float v2f __attribute__((ext_vector_type(2)));

__global__ void pack_kernel(const float* __restrict__ z0,
                            const float* __restrict__ v0,
                            float* __restrict__ xs, float* __restrict__ ys,
                            float* __restrict__ vxs, float* __restrict__ vys,
                            float4* __restrict__ pts, int n_pts) {
    int p = blockIdx.x * blockDim.x + threadIdx.x;
    if (p < n_pts) {
        float zx = z0[2 * p], zy = z0[2 * p + 1];
        float vx = v0[2 * p], vy = v0[2 * p + 1];
        xs[p] = zx; ys[p] = zy; vxs[p] = vx; vys[p] = vy;
        pts[p] = make_float4(zx, zy, vx, vy);
    }
}

// A&S 7.1.28: erf(x) = sgn(x)*(1 - u^-16), |err| <= 3e-7.  R11/R12-verified.
#define ERF_A1 0.0705230784f
#define ERF_A2 0.0422820123f
#define ERF_A3 0.0092705272f
#define ERF_A4 0.0001520143f
#define ERF_A5 0.0002765672f
#define ERF_A6 0.0000430638f

__device__ __forceinline__ float erf728(float x) {
    float ax = fabsf(x);
    float h = fmaf(ERF_A6, ax, ERF_A5);
    h = fmaf(h, ax, ERF_A4);
    h = fmaf(h, ax, ERF_A3);
    h = fmaf(h, ax, ERF_A2);
    h = fmaf(h, ax, ERF_A1);
    float u = fmaf(h, ax, 1.0f);
    float w = __builtin_amdgcn_rcpf(u);
    w = w * w; w = w * w; w = w * w; w = w * w;   // u^-16
    return copysignf(1.0f - w, x);
}

__device__ __forceinline__ float pair_val(float4 Pi, float4 Pj,
                                          float b, float t0, float tn) {
    const float SPI2 = 0.88622692545275801365f;
    const float L2E  = 1.4426950408889634f;
    float dzx = Pi.x - Pj.x, dzy = Pi.y - Pj.y;
    float dvx = Pi.z - Pj.z, dvy = Pi.w - Pj.w;
    float a2 = fmaf(dzx, dzx, dzy * dzy);
    float b2 = fmaf(dvx, dvx, dvy * dvy);
    float ab = fmaf(dzx, dvx, dzy * dvy);
    float r  = __builtin_amdgcn_rsqf(b2);
    float mu = ab * (r * r);
    float e0 = fmaf(ab, mu, b - a2);
    float E  = __builtin_amdgcn_exp2f(e0 * L2E);
    float bn = b2 * r;
    float x1 = bn * (tn + mu);
    float x0 = bn * (t0 + mu);
    return (E * (SPI2 * r)) * (erf728(x1) - erf728(x0));
}

__device__ __forceinline__ v2f erf_u2(v2f ax) {
    v2f h = ERF_A6 * ax + ERF_A5;
    h = h * ax + ERF_A4;
    h = h * ax + ERF_A3;
    h = h * ax + ERF_A2;
    h = h * ax + ERF_A1;
    return h * ax + 1.0f;
}

__device__ __forceinline__ v2f pair_val2(float Pix, float Piy, float Pivx,
                                         float Pivy, v2f xj, v2f yj, v2f vxj,
                                         v2f vyj, float b, float t0, float tn) {
    const float SPI2 = 0.88622692545275801365f;
    const float L2E  = 1.4426950408889634f;
    v2f dzx = Pix - xj, dzy = Piy - yj;
    v2f dvx = Pivx - vxj, dvy = Pivy - vyj;
    v2f a2 = dzx * dzx + dzy * dzy;
    v2f b2 = dvx * dvx + dvy * dvy;
    v2f ab = dzx * dvx + dzy * dvy;
    v2f r;  r.x = __builtin_amdgcn_rsqf(b2.x); r.y = __builtin_amdgcn_rsqf(b2.y);
    v2f mu = ab * (r * r);
    v2f e0 = ab * mu + (b - a2);
    v2f E;  E.x = __builtin_amdgcn_exp2f(e0.x * L2E);
            E.y = __builtin_amdgcn_exp2f(e0.y * L2E);
    v2f bn = b2 * r;
    v2f x1 = bn * (tn + mu);
    v2f x0 = bn * (t0 + mu);
    v2f ax1; ax1.x = fabsf(x1.x); ax1.y = fabsf(x1.y);
    v2f ax0; ax0.x = fabsf(x0.x); ax0.y = fabsf(x0.y);
    v2f u1 = erf_u2(ax1);
    v2f u0 = erf_u2(ax0);
    v2f p = u1 * u0;
    v2f rp; rp.x = __builtin_amdgcn_rcpf(p.x); rp.y = __builtin_amdgcn_rcpf(p.y);
    v2f w1 = u0 * rp;
    v2f w0 = u1 * rp;
    w1 = w1 * w1; w1 = w1 * w1; w1 = w1 * w1; w1 = w1 * w1;
    w0 = w0 * w0; w0 = w0 * w0; w0 = w0 * w0; w0 = w0 * w0;
    v2f e1 = 1.0f - w1;
    v2f e0f = 1.0f - w0;
    e1.x = copysignf(e1.x, x1.x);  e1.y = copysignf(e1.y, x1.y);
    e0f.x = copysignf(e0f.x, x0.x); e0f.y = copysignf(e0f.y, x0.y);
    return (E * (r * SPI2)) * (e1 - e0f);
}

__device__ __forceinline__ float row_sweep(const float* __restrict__ xs,
                                           const float* __restrict__ ys,
                                           const float* __restrict__ vxs,
                                           const float* __restrict__ vys,
                                           const float4* __restrict__ pts,
                                           int r, int n_pts,
                                           float b, float t0, float tn) {
    float4 Pi = pts[r];
    float head = 0.0f;
    int base = r + 1;
    if (base & 1) {
        if (threadIdx.x == 0)
            head = pair_val(Pi, pts[base], b, t0, tn);
        ++base;
    }
    v2f acc = {0.f, 0.f};
    for (int jb = base + 2 * (int)threadIdx.x; jb < n_pts; jb += 2 * NTHR) {
        v2f xj  = *(const v2f*)(xs + jb);
        v2f yj  = *(const v2f*)(ys + jb);
        v2f vxj = *(const v2f*)(vxs + jb);
        v2f vyj = *(const v2f*)(vys + jb);
        acc += pair_val2(Pi.x, Pi.y, Pi.z, Pi.w, xj, yj, vxj, vyj, b, t0, tn);
    }
    return head + acc.x + acc.y;
}

// Event pass, start block s (shift is bijective over blocks).
__device__ __forceinline__ float event_sum(const int2* __restrict__ idx,
                                           const float* __restrict__ t,
                                           const float4* __restrict__ pts,
                                           int n_events, int nblocks, int s) {
    const int4*   idx4 = (const int4*)idx;
    const float2* t2   = (const float2*)t;
    const int half = n_events >> 1;
    float acc = 0.0f;
    for (int h = s * NTHR + threadIdx.x; h < half; h += nblocks * NTHR) {
        int4 ij = idx4[h];
        float2 tt = t2[h];
        float4 pi0 = pts[ij.x], pj0 = pts[ij.y];
        float4 pi1 = pts[ij.z], pj1 = pts[ij.w];
        float dx0 = (pi0.x - pj0.x) + (pi0.z - pj0.z) * tt.x;
        float dy0 = (pi0.y - pj0.y) + (pi0.w - pj0.w) * tt.x;
        float dx1 = (pi1.x - pj1.x) + (pi1.z - pj1.z) * tt.y;
        float dy1 = (pi1.y - pj1.y) + (pi1.w - pj1.w) * tt.y;
        acc = fmaf(dx0, dx0, fmaf(dy0, dy0, acc));
        acc = fmaf(dx1, dx1, fmaf(dy1, dy1, acc));
    }
    if ((n_events & 1) && s == 0 && threadIdx.x == 0) {
        int e = n_events - 1;
        int2 ij = idx[e];
        float te = t[e];
        float4 pi = pts[ij.x], pj = pts[ij.y];
        float dx = (pi.x - pj.x) + (pi.z - pj.z) * te;
        float dy = (pi.y - pj.y) + (pi.w - pj.w) * te;
        acc = fmaf(dx, dx, fmaf(dy, dy, acc));
    }
    return acc;
}

// Pair pass for row-pair unit u: rows {u, n_rows-1-u} (R5 balance).
__device__ __forceinline__ float pair_sum(const float* __restrict__ xs,
                                          const float* __restrict__ ys,
                                          const float* __restrict__ vxs,
                                          const float* __restrict__ vys,
                                          const float4* __restrict__ pts,
                                          int n_pts, float b, float t0,
                                          float tn, int u) {
    const int n_rows = n_pts - 1;
    const int r1 = u;
    float acc = 0.0f;
    if (r1 < n_rows) {
        const int r2 = n_rows - 1 - r1;
        acc += row_sweep(xs, ys, vxs, vys, pts, r1, n_pts, b, t0, tn);
        if (r2 > r1)
            acc += row_sweep(xs, ys, vxs, vys, pts, r2, n_pts, b, t0, tn);
    }
    return acc;
}

// ATTRIBUTION BUILD: production R12 structure, whole body replicated REPS
// times with bijective per-rep rotation (pairs: +613 mod nblk, gcd(613,2500)=1;
// events: start shift). Sum / REPS. Lifts the fused kernel above the 40us
// fill floor so rocprof reports its VALUBusy/Occupancy/FETCH.
__global__ __launch_bounds__(NTHR) void cvm_main_kernel(
    const int2* __restrict__ idx, const float* __restrict__ t,
    const float* __restrict__ xs, const float* __restrict__ ys,
    const float* __restrict__ vxs, const float* __restrict__ vys,
    const float4* __restrict__ pts,
    const float* __restrict__ t0p, const float* __restrict__ tnp,
    const float* __restrict__ betap,
    int n_events, int n_pts, double* __restrict__ partials) {

    const float b  = betap[0];
    const float t0 = t0p[0];
    const float tn = tnp[0];
    const int nblocks = gridDim.x;

    float accf = 0.0f;
    #pragma unroll 1
    for (int rep = 0; rep < REPS; ++rep) {
        int u = blockIdx.x + rep * 613;
        while (u >= nblocks) u -= nblocks;      // 613*3 < 2*2500
        int s = blockIdx.x + rep * 625;
        while (s >= nblocks) s -= nblocks;
        if (blockIdx.x & 1) {
            accf += pair_sum(xs, ys, vxs, vys, pts, n_pts, b, t0, tn, u);
            accf += event_sum(idx, t, pts, n_events, nblocks, s);
        } else {
            accf += event_sum(idx, t, pts, n_events, nblocks, s);
            accf += pair_sum(xs, ys, vxs, vys, pts, n_pts, b, t0, tn, u);
        }
    }

    double v = (double)accf * (1.0 / REPS);
    #pragma unroll
    for (int off = 32; off > 0; off >>= 1) v += __shfl_down(v, off, 64);
    __shared__ double wsum[4];
    if ((threadIdx.x & 63) == 0) wsum[threadIdx.x >> 6] = v;
    __syncthreads();
    if (threadIdx.x == 0)
        partials[blockIdx.x] = wsum[0] + wsum[1] + wsum[2] + wsum[3];
}

__global__ void finish_kernel(const double* __restrict__ partials, int nblk,
                              const float* __restrict__ betap,
                              float* __restrict__ out, int n_events) {
    double v = 0.0;
    for (int i = threadIdx.x; i < nblk; i += NTHR) v += partials[i];
    #pragma unroll
    for (int off = 32; off > 0; off >>= 1) v += __shfl_down(v, off, 64);
    __shared__ double wsum[4];
    if ((threadIdx.x & 63) == 0) wsum[threadIdx.x >> 6] = v;
    __syncthreads();
    if (threadIdx.x == 0)
        out[0] = (float)((double)n_events * (double)betap[0] -
                         (wsum[0] + wsum[1] + wsum[2] + wsum[3]));
}

extern "C" void kernel_launch(void* const* d_in, const int* in_sizes, int n_in,
                              void* d_out, int out_size, void* d_ws, size_t ws_size,
                              hipStream_t stream) {
    const int2*  idx  = (const int2*)d_in[0];
    const float* t    = (const float*)d_in[1];
    const float* t0   = (const float*)d_in[2];
    const float* tn   = (const float*)d_in[3];
    const float* z0   = (const float*)d_in[4];
    const float* v0   = (const float*)d_in[5];
    const float* beta = (const float*)d_in[6];
    const int n_events = in_sizes[1];
    const int n_pts    = in_sizes[4] / 2;

    char* base = (char*)d_ws;
    double* partials = (double*)base;
    float* xs  = (float*)(base + 32768);
    float* ys  = (float*)(base + 32768 + PTS_PAD);
    float* vxs = (float*)(base + 32768 + 2 * PTS_PAD);
    float* vys = (float*)(base + 32768 + 3 * PTS_PAD);
    float4* pts = (float4*)(base + 32768 + 4 * PTS_PAD);

    const int n_rows = n_pts - 1;
    int nblk = (n_rows + 1) / 2;          // 2500 for n_pts=5000
    if (nblk < 1) nblk = 1;
    if (nblk > MAXBLK) nblk = MAXBLK;

    pack_kernel<<<(n_pts + NTHR - 1) / NTHR, NTHR, 0, stream>>>(
        z0, v0, xs, ys, vxs, vys, pts, n_pts);
    cvm_main_kernel<<<nblk, NTHR, 0, stream>>>(idx, t, xs, ys, vxs, vys, pts,
                                               t0, tn, beta, n_events, n_pts,
                                               partials);
    finish_kernel<<<1, NTHR, 0, stream>>>(partials, nblk, beta,
                                          (float*)d_out, n_events);
}

// Round 14
// 136.035 us; speedup vs baseline: 1.1189x; 1.1189x over previous
//
#include <hip/hip_runtime.h>
#include <math.h>

#define NTHR 256
#define MAXBLK 4096
#define PTS_PAD 20480   // bytes per SoA array slot (>= 5000*4, 16B-aligned)

// ws layout: [0, MAXBLK*8) double partials; [MAXBLK*8, +4) counter;
//            [32768 .. +4*PTS_PAD) SoA arrays x,y,vx,vy;
//            [32768+4*PTS_PAD ...) float4 pts (AoS, for event gathers)

typedef float v2f __attribute__((ext_vector_type(2)));

__global__ void pack_kernel(const float* __restrict__ z0,
                            const float* __restrict__ v0,
                            float* __restrict__ xs, float* __restrict__ ys,
                            float* __restrict__ vxs, float* __restrict__ vys,
                            float4* __restrict__ pts,
                            unsigned int* __restrict__ counter, int n_pts) {
    int p = blockIdx.x * blockDim.x + threadIdx.x;
    if (p < n_pts) {
        float zx = z0[2 * p], zy = z0[2 * p + 1];
        float vx = v0[2 * p], vy = v0[2 * p + 1];
        xs[p] = zx; ys[p] = zy; vxs[p] = vx; vys[p] = vy;
        pts[p] = make_float4(zx, zy, vx, vy);
    }
    if (p == 0) *counter = 0u;
}

// A&S 7.1.28: erf(x) = sgn(x)*(1 - u^-16), |err| <= 3e-7.  R11-R13-verified.
#define ERF_A1 0.0705230784f
#define ERF_A2 0.0422820123f
#define ERF_A3 0.0092705272f
#define ERF_A4 0.0001520143f
#define ERF_A5 0.0002765672f
#define ERF_A6 0.0000430638f

__device__ __forceinline__ float erf728(float x) {
    float ax = fabsf(x);
    float h = fmaf(ERF_A6, ax, ERF_A5);
    h = fmaf(h, ax, ERF_A4);
    h = fmaf(h, ax, ERF_A3);
    h = fmaf(h, ax, ERF_A2);
    h = fmaf(h, ax, ERF_A1);
    float u = fmaf(h, ax, 1.0f);
    float w = __builtin_amdgcn_rcpf(u);
    w = w * w; w = w * w; w = w * w; w = w * w;   // u^-16
    return copysignf(1.0f - w, x);
}

__device__ __forceinline__ float pair_val(float4 Pi, float4 Pj,
                                          float b, float t0, float tn) {
    const float SPI2 = 0.88622692545275801365f;
    const float L2E  = 1.4426950408889634f;
    float dzx = Pi.x - Pj.x, dzy = Pi.y - Pj.y;
    float dvx = Pi.z - Pj.z, dvy = Pi.w - Pj.w;
    float a2 = fmaf(dzx, dzx, dzy * dzy);
    float b2 = fmaf(dvx, dvx, dvy * dvy);
    float ab = fmaf(dzx, dvx, dzy * dvy);
    float r  = __builtin_amdgcn_rsqf(b2);
    float mu = ab * (r * r);
    float e0 = fmaf(ab, mu, b - a2);
    float E  = __builtin_amdgcn_exp2f(e0 * L2E);
    float bn = b2 * r;
    float x1 = bn * (tn + mu);
    float x0 = bn * (t0 + mu);
    return (E * (SPI2 * r)) * (erf728(x1) - erf728(x0));
}

__device__ __forceinline__ v2f erf_u2(v2f ax) {
    v2f h = ERF_A6 * ax + ERF_A5;
    h = h * ax + ERF_A4;
    h = h * ax + ERF_A3;
    h = h * ax + ERF_A2;
    h = h * ax + ERF_A1;
    return h * ax + 1.0f;
}

__device__ __forceinline__ v2f pair_val2(float Pix, float Piy, float Pivx,
                                         float Pivy, v2f xj, v2f yj, v2f vxj,
                                         v2f vyj, float b, float t0, float tn) {
    const float SPI2 = 0.88622692545275801365f;
    const float L2E  = 1.4426950408889634f;
    v2f dzx = Pix - xj, dzy = Piy - yj;
    v2f dvx = Pivx - vxj, dvy = Pivy - vyj;
    v2f a2 = dzx * dzx + dzy * dzy;
    v2f b2 = dvx * dvx + dvy * dvy;
    v2f ab = dzx * dvx + dzy * dvy;
    v2f r;  r.x = __builtin_amdgcn_rsqf(b2.x); r.y = __builtin_amdgcn_rsqf(b2.y);
    v2f mu = ab * (r * r);
    v2f e0 = ab * mu + (b - a2);
    v2f E;  E.x = __builtin_amdgcn_exp2f(e0.x * L2E);
            E.y = __builtin_amdgcn_exp2f(e0.y * L2E);
    v2f bn = b2 * r;
    v2f x1 = bn * (tn + mu);
    v2f x0 = bn * (t0 + mu);
    v2f ax1; ax1.x = fabsf(x1.x); ax1.y = fabsf(x1.y);
    v2f ax0; ax0.x = fabsf(x0.x); ax0.y = fabsf(x0.y);
    v2f u1 = erf_u2(ax1);
    v2f u0 = erf_u2(ax0);
    v2f p = u1 * u0;
    v2f rp; rp.x = __builtin_amdgcn_rcpf(p.x); rp.y = __builtin_amdgcn_rcpf(p.y);
    v2f w1 = u0 * rp;
    v2f w0 = u1 * rp;
    w1 = w1 * w1; w1 = w1 * w1; w1 = w1 * w1; w1 = w1 * w1;
    w0 = w0 * w0; w0 = w0 * w0; w0 = w0 * w0; w0 = w0 * w0;
    v2f e1 = 1.0f - w1;
    v2f e0f = 1.0f - w0;
    e1.x = copysignf(e1.x, x1.x);  e1.y = copysignf(e1.y, x1.y);
    e0f.x = copysignf(e0f.x, x0.x); e0f.y = copysignf(e0f.y, x0.y);
    return (E * (r * SPI2)) * (e1 - e0f);
}

__device__ __forceinline__ float row_sweep(const float* __restrict__ xs,
                                           const float* __restrict__ ys,
                                           const float* __restrict__ vxs,
                                           const float* __restrict__ vys,
                                           const float4* __restrict__ pts,
                                           int r, int n_pts,
                                           float b, float t0, float tn) {
    float4 Pi = pts[r];
    float head = 0.0f;
    int base = r + 1;
    if (base & 1) {
        if (threadIdx.x == 0)
            head = pair_val(Pi, pts[base], b, t0, tn);
        ++base;
    }
    v2f acc = {0.f, 0.f};
    for (int jb = base + 2 * (int)threadIdx.x; jb < n_pts; jb += 2 * NTHR) {
        v2f xj  = *(const v2f*)(xs + jb);
        v2f yj  = *(const v2f*)(ys + jb);
        v2f vxj = *(const v2f*)(vxs + jb);
        v2f vyj = *(const v2f*)(vys + jb);
        acc += pair_val2(Pi.x, Pi.y, Pi.z, Pi.w, xj, yj, vxj, vyj, b, t0, tn);
    }
    return head + acc.x + acc.y;
}

__device__ __forceinline__ float pair_sum(const float* __restrict__ xs,
                                          const float* __restrict__ ys,
                                          const float* __restrict__ vxs,
                                          const float* __restrict__ vys,
                                          const float4* __restrict__ pts,
                                          int n_pts, float b, float t0,
                                          float tn) {
    const int n_rows = n_pts - 1;
    const int r1 = blockIdx.x;
    float acc = 0.0f;
    if (r1 < n_rows) {
        const int r2 = n_rows - 1 - r1;
        acc += row_sweep(xs, ys, vxs, vys, pts, r1, n_pts, b, t0, tn);
        if (r2 > r1)
            acc += row_sweep(xs, ys, vxs, vys, pts, r2, n_pts, b, t0, tn);
    }
    return acc;
}

__global__ __launch_bounds__(NTHR) void cvm_main_kernel(
    const int2* __restrict__ idx, const float* __restrict__ t,
    const float* __restrict__ xs, const float* __restrict__ ys,
    const float* __restrict__ vxs, const float* __restrict__ vys,
    const float4* __restrict__ pts,
    const float* __restrict__ t0p, const float* __restrict__ tnp,
    const float* __restrict__ betap,
    int n_events, int n_pts,
    double* __restrict__ partials, unsigned int* __restrict__ counter,
    float* __restrict__ out) {

    const float b  = betap[0];
    const float t0 = t0p[0];
    const float tn = tnp[0];
    const int nblocks = gridDim.x;
    const int tid = blockIdx.x * NTHR + (int)threadIdx.x;
    const int nthreads = nblocks * NTHR;

    // ---- HOIST event loads above the pair sweep. 1.56 events/thread ->
    // one int4+float2+4xfloat4 gather set per thread, consumed AFTER the
    // ~14us pair loop: gather latency fully hidden in-wave (vmcnt FIFO:
    // these retire long before the pair loop's own load waits).
    const int4*   idx4 = (const int4*)idx;
    const float2* t2   = (const float2*)t;
    const int half = n_events >> 1;
    const bool hasev = tid < half;
    int4 ij; float2 tt;
    float4 pi0, pj0, pi1, pj1;
    if (hasev) {
        ij = idx4[tid];
        tt = t2[tid];
        pi0 = pts[ij.x]; pj0 = pts[ij.y];
        pi1 = pts[ij.z]; pj1 = pts[ij.w];
    }

    // ---- Pair sweep (R12 math, unchanged)
    float accf = pair_sum(xs, ys, vxs, vys, pts, n_pts, b, t0, tn);

    // ---- Consume hoisted events
    if (hasev) {
        float dx0 = (pi0.x - pj0.x) + (pi0.z - pj0.z) * tt.x;
        float dy0 = (pi0.y - pj0.y) + (pi0.w - pj0.w) * tt.x;
        float dx1 = (pi1.x - pj1.x) + (pi1.z - pj1.z) * tt.y;
        float dy1 = (pi1.y - pj1.y) + (pi1.w - pj1.w) * tt.y;
        accf = fmaf(dx0, dx0, fmaf(dy0, dy0, accf));
        accf = fmaf(dx1, dx1, fmaf(dy1, dy1, accf));
    }
    // residual (empty at this size; kept for generality)
    for (int h = tid + nthreads; h < half; h += nthreads) {
        int4 ij2 = idx4[h];
        float2 tt2 = t2[h];
        float4 a0 = pts[ij2.x], b0 = pts[ij2.y];
        float4 a1 = pts[ij2.z], b1 = pts[ij2.w];
        float dx0 = (a0.x - b0.x) + (a0.z - b0.z) * tt2.x;
        float dy0 = (a0.y - b0.y) + (a0.w - b0.w) * tt2.x;
        float dx1 = (a1.x - b1.x) + (a1.z - b1.z) * tt2.y;
        float dy1 = (a1.y - b1.y) + (a1.w - b1.w) * tt2.y;
        accf = fmaf(dx0, dx0, fmaf(dy0, dy0, accf));
        accf = fmaf(dx1, dx1, fmaf(dy1, dy1, accf));
    }
    if ((n_events & 1) && tid == 0) {
        int e = n_events - 1;
        int2 ij1 = idx[e];
        float te = t[e];
        float4 pi = pts[ij1.x], pj = pts[ij1.y];
        float dx = (pi.x - pj.x) + (pi.z - pj.z) * te;
        float dy = (pi.y - pj.y) + (pi.w - pj.w) * te;
        accf = fmaf(dx, dx, fmaf(dy, dy, accf));
    }

    // ---- Block reduce (double), last-block finish (R2-proven pattern)
    double v = (double)accf;
    #pragma unroll
    for (int off = 32; off > 0; off >>= 1) v += __shfl_down(v, off, 64);
    __shared__ double wsum[4];
    __shared__ bool is_last;
    if ((threadIdx.x & 63) == 0) wsum[threadIdx.x >> 6] = v;
    __syncthreads();
    if (threadIdx.x == 0) {
        partials[blockIdx.x] = wsum[0] + wsum[1] + wsum[2] + wsum[3];
        __threadfence();
        unsigned int old = atomicAdd(counter, 1u);
        is_last = (old == (unsigned int)(nblocks - 1));
    }
    __syncthreads();
    if (is_last) {
        __threadfence();
        double s = 0.0;
        for (int i = threadIdx.x; i < nblocks; i += NTHR) s += partials[i];
        #pragma unroll
        for (int off = 32; off > 0; off >>= 1) s += __shfl_down(s, off, 64);
        if ((threadIdx.x & 63) == 0) wsum[threadIdx.x >> 6] = s;
        __syncthreads();
        if (threadIdx.x == 0)
            out[0] = (float)((double)n_events * (double)betap[0] -
                             (wsum[0] + wsum[1] + wsum[2] + wsum[3]));
    }
}

extern "C" void kernel_launch(void* const* d_in, const int* in_sizes, int n_in,
                              void* d_out, int out_size, void* d_ws, size_t ws_size,
                              hipStream_t stream) {
    const int2*  idx  = (const int2*)d_in[0];
    const float* t    = (const float*)d_in[1];
    const float* t0   = (const float*)d_in[2];
    const float* tn   = (const float*)d_in[3];
    const float* z0   = (const float*)d_in[4];
    const float* v0   = (const float*)d_in[5];
    const float* beta = (const float*)d_in[6];
    const int n_events = in_sizes[1];
    const int n_pts    = in_sizes[4] / 2;

    char* base = (char*)d_ws;
    double* partials = (double*)base;
    unsigned int* counter = (unsigned int*)(base + MAXBLK * sizeof(double));
    float* xs  = (float*)(base + 32768);
    float* ys  = (float*)(base + 32768 + PTS_PAD);
    float* vxs = (float*)(base + 32768 + 2 * PTS_PAD);
    float* vys = (float*)(base + 32768 + 3 * PTS_PAD);
    float4* pts = (float4*)(base + 32768 + 4 * PTS_PAD);

    const int n_rows = n_pts - 1;
    int nblk = (n_rows + 1) / 2;          // 2500 for n_pts=5000
    if (nblk < 1) nblk = 1;
    if (nblk > MAXBLK) nblk = MAXBLK;

    pack_kernel<<<(n_pts + NTHR - 1) / NTHR, NTHR, 0, stream>>>(
        z0, v0, xs, ys, vxs, vys, pts, counter, n_pts);
    cvm_main_kernel<<<nblk, NTHR, 0, stream>>>(idx, t, xs, ys, vxs, vys, pts,
                                               t0, tn, beta, n_events, n_pts,
                                               partials, counter, (float*)d_out);
}

// Round 15
// 96.604 us; speedup vs baseline: 1.5756x; 1.4082x over previous
//
#include <hip/hip_runtime.h>
#include <math.h>

#define NTHR 256
#define MAXBLK 4096
#define PTS_PAD 20480   // bytes per SoA array slot (>= 5000*4, 16B-aligned)

// ws layout: [0, MAXBLK*8) double partials;
//            [32768 .. +4*PTS_PAD) SoA arrays x,y,vx,vy (float each);
//            [32768+4*PTS_PAD ...) float4 pts (AoS, for event gathers)

typedef float v2f __attribute__((ext_vector_type(2)));

__global__ void pack_kernel(const float* __restrict__ z0,
                            const float* __restrict__ v0,
                            float* __restrict__ xs, float* __restrict__ ys,
                            float* __restrict__ vxs, float* __restrict__ vys,
                            float4* __restrict__ pts, int n_pts) {
    int p = blockIdx.x * blockDim.x + threadIdx.x;
    if (p < n_pts) {
        float zx = z0[2 * p], zy = z0[2 * p + 1];
        float vx = v0[2 * p], vy = v0[2 * p + 1];
        xs[p] = zx; ys[p] = zy; vxs[p] = vx; vys[p] = vy;
        pts[p] = make_float4(zx, zy, vx, vy);
    }
}

// A&S 7.1.28: erf(x) = sgn(x)*(1 - u^-16), |err| <= 3e-7.  R11-R13-verified.
#define ERF_A1 0.0705230784f
#define ERF_A2 0.0422820123f
#define ERF_A3 0.0092705272f
#define ERF_A4 0.0001520143f
#define ERF_A5 0.0002765672f
#define ERF_A6 0.0000430638f

__device__ __forceinline__ float erf728(float x) {
    float ax = fabsf(x);
    float h = fmaf(ERF_A6, ax, ERF_A5);
    h = fmaf(h, ax, ERF_A4);
    h = fmaf(h, ax, ERF_A3);
    h = fmaf(h, ax, ERF_A2);
    h = fmaf(h, ax, ERF_A1);
    float u = fmaf(h, ax, 1.0f);
    float w = __builtin_amdgcn_rcpf(u);
    w = w * w; w = w * w; w = w * w; w = w * w;   // u^-16
    return copysignf(1.0f - w, x);
}

__device__ __forceinline__ float pair_val(float4 Pi, float4 Pj,
                                          float b, float t0, float tn) {
    const float SPI2 = 0.88622692545275801365f;
    const float L2E  = 1.4426950408889634f;
    float dzx = Pi.x - Pj.x, dzy = Pi.y - Pj.y;
    float dvx = Pi.z - Pj.z, dvy = Pi.w - Pj.w;
    float a2 = fmaf(dzx, dzx, dzy * dzy);
    float b2 = fmaf(dvx, dvx, dvy * dvy);
    float ab = fmaf(dzx, dvx, dzy * dvy);
    float r  = __builtin_amdgcn_rsqf(b2);
    float mu = ab * (r * r);
    float e0 = fmaf(ab, mu, b - a2);
    float E  = __builtin_amdgcn_exp2f(e0 * L2E);
    float bn = b2 * r;
    float x1 = bn * (tn + mu);
    float x0 = bn * (t0 + mu);
    return (E * (SPI2 * r)) * (erf728(x1) - erf728(x0));
}

__device__ __forceinline__ v2f erf_u2(v2f ax) {
    v2f h = ERF_A6 * ax + ERF_A5;
    h = h * ax + ERF_A4;
    h = h * ax + ERF_A3;
    h = h * ax + ERF_A2;
    h = h * ax + ERF_A1;
    return h * ax + 1.0f;
}

__device__ __forceinline__ v2f pair_val2(float Pix, float Piy, float Pivx,
                                         float Pivy, v2f xj, v2f yj, v2f vxj,
                                         v2f vyj, float b, float t0, float tn) {
    const float SPI2 = 0.88622692545275801365f;
    const float L2E  = 1.4426950408889634f;
    v2f dzx = Pix - xj, dzy = Piy - yj;
    v2f dvx = Pivx - vxj, dvy = Pivy - vyj;
    v2f a2 = dzx * dzx + dzy * dzy;
    v2f b2 = dvx * dvx + dvy * dvy;
    v2f ab = dzx * dvx + dzy * dvy;
    v2f r;  r.x = __builtin_amdgcn_rsqf(b2.x); r.y = __builtin_amdgcn_rsqf(b2.y);
    v2f mu = ab * (r * r);
    v2f e0 = ab * mu + (b - a2);
    v2f E;  E.x = __builtin_amdgcn_exp2f(e0.x * L2E);
            E.y = __builtin_amdgcn_exp2f(e0.y * L2E);
    v2f bn = b2 * r;
    v2f x1 = bn * (tn + mu);
    v2f x0 = bn * (t0 + mu);
    v2f ax1; ax1.x = fabsf(x1.x); ax1.y = fabsf(x1.y);
    v2f ax0; ax0.x = fabsf(x0.x); ax0.y = fabsf(x0.y);
    v2f u1 = erf_u2(ax1);
    v2f u0 = erf_u2(ax0);
    v2f p = u1 * u0;
    v2f rp; rp.x = __builtin_amdgcn_rcpf(p.x); rp.y = __builtin_amdgcn_rcpf(p.y);
    v2f w1 = u0 * rp;
    v2f w0 = u1 * rp;
    w1 = w1 * w1; w1 = w1 * w1; w1 = w1 * w1; w1 = w1 * w1;
    w0 = w0 * w0; w0 = w0 * w0; w0 = w0 * w0; w0 = w0 * w0;
    v2f e1 = 1.0f - w1;
    v2f e0f = 1.0f - w0;
    e1.x = copysignf(e1.x, x1.x);  e1.y = copysignf(e1.y, x1.y);
    e0f.x = copysignf(e0f.x, x0.x); e0f.y = copysignf(e0f.y, x0.y);
    return (E * (r * SPI2)) * (e1 - e0f);
}

__device__ __forceinline__ float row_sweep(const float* __restrict__ xs,
                                           const float* __restrict__ ys,
                                           const float* __restrict__ vxs,
                                           const float* __restrict__ vys,
                                           const float4* __restrict__ pts,
                                           int r, int n_pts,
                                           float b, float t0, float tn) {
    float4 Pi = pts[r];
    float head = 0.0f;
    int base = r + 1;
    if (base & 1) {
        if (threadIdx.x == 0)
            head = pair_val(Pi, pts[base], b, t0, tn);
        ++base;
    }
    v2f acc = {0.f, 0.f};
    for (int jb = base + 2 * (int)threadIdx.x; jb < n_pts; jb += 2 * NTHR) {
        v2f xj  = *(const v2f*)(xs + jb);
        v2f yj  = *(const v2f*)(ys + jb);
        v2f vxj = *(const v2f*)(vxs + jb);
        v2f vyj = *(const v2f*)(vys + jb);
        acc += pair_val2(Pi.x, Pi.y, Pi.z, Pi.w, xj, yj, vxj, vyj, b, t0, tn);
    }
    return head + acc.x + acc.y;
}

// Event part: 2 events/thread-iter, int4+float2 loads, 4 gathers in flight.
__device__ __forceinline__ float event_sum(const int2* __restrict__ idx,
                                           const float* __restrict__ t,
                                           const float4* __restrict__ pts,
                                           int n_events, int nblocks) {
    const int4*   idx4 = (const int4*)idx;
    const float2* t2   = (const float2*)t;
    const int half = n_events >> 1;
    float acc = 0.0f;
    for (int h = blockIdx.x * NTHR + threadIdx.x; h < half;
         h += nblocks * NTHR) {
        int4 ij = idx4[h];
        float2 tt = t2[h];
        float4 pi0 = pts[ij.x], pj0 = pts[ij.y];
        float4 pi1 = pts[ij.z], pj1 = pts[ij.w];
        float dx0 = (pi0.x - pj0.x) + (pi0.z - pj0.z) * tt.x;
        float dy0 = (pi0.y - pj0.y) + (pi0.w - pj0.w) * tt.x;
        float dx1 = (pi1.x - pj1.x) + (pi1.z - pj1.z) * tt.y;
        float dy1 = (pi1.y - pj1.y) + (pi1.w - pj1.w) * tt.y;
        acc = fmaf(dx0, dx0, fmaf(dy0, dy0, acc));
        acc = fmaf(dx1, dx1, fmaf(dy1, dy1, acc));
    }
    if ((n_events & 1) && blockIdx.x == 0 && threadIdx.x == 0) {
        int e = n_events - 1;
        int2 ij = idx[e];
        float te = t[e];
        float4 pi = pts[ij.x], pj = pts[ij.y];
        float dx = (pi.x - pj.x) + (pi.z - pj.z) * te;
        float dy = (pi.y - pj.y) + (pi.w - pj.w) * te;
        acc = fmaf(dx, dx, fmaf(dy, dy, acc));
    }
    return acc;
}

// Pair part: block b owns rows {b, n_rows-1-b} (perfect balance, R5 scheme).
__device__ __forceinline__ float pair_sum(const float* __restrict__ xs,
                                          const float* __restrict__ ys,
                                          const float* __restrict__ vxs,
                                          const float* __restrict__ vys,
                                          const float4* __restrict__ pts,
                                          int n_pts, float b, float t0,
                                          float tn) {
    const int n_rows = n_pts - 1;
    const int r1 = blockIdx.x;
    float acc = 0.0f;
    if (r1 < n_rows) {
        const int r2 = n_rows - 1 - r1;
        acc += row_sweep(xs, ys, vxs, vys, pts, r1, n_pts, b, t0, tn);
        if (r2 > r1)
            acc += row_sweep(xs, ys, vxs, vys, pts, r2, n_pts, b, t0, tn);
    }
    return acc;
}

__global__ __launch_bounds__(NTHR) void cvm_main_kernel(
    const int2* __restrict__ idx, const float* __restrict__ t,
    const float* __restrict__ xs, const float* __restrict__ ys,
    const float* __restrict__ vxs, const float* __restrict__ vys,
    const float4* __restrict__ pts,
    const float* __restrict__ t0p, const float* __restrict__ tnp,
    const float* __restrict__ betap,
    int n_events, int n_pts, double* __restrict__ partials) {

    const float b  = betap[0];
    const float t0 = t0p[0];
    const float tn = tnp[0];
    const int nblocks = gridDim.x;

    // PHASE PARITY BY WAVE (fix of R8's block parity): blocks map to CUs as
    // c, c+256, c+512... and 256 is even, so blockIdx&1 gives every CU a
    // single phase order (no intra-CU overlap — why R8 only won ~2us).
    // Wave parity guarantees a 50/50 mix of {events-first, pairs-first}
    // waves on EVERY CU: the ~7us event gather stall is covered by pair
    // VALU issue from sibling waves (m114 co-schedule). Wave-uniform
    // branch -> no lane divergence; indexing identical in both orders.
    float accf;
    if ((threadIdx.x >> 6) & 1) {
        accf = pair_sum(xs, ys, vxs, vys, pts, n_pts, b, t0, tn);
        accf += event_sum(idx, t, pts, n_events, nblocks);
    } else {
        accf = event_sum(idx, t, pts, n_events, nblocks);
        accf += pair_sum(xs, ys, vxs, vys, pts, n_pts, b, t0, tn);
    }

    double v = (double)accf;
    #pragma unroll
    for (int off = 32; off > 0; off >>= 1) v += __shfl_down(v, off, 64);
    __shared__ double wsum[4];
    if ((threadIdx.x & 63) == 0) wsum[threadIdx.x >> 6] = v;
    __syncthreads();
    if (threadIdx.x == 0)
        partials[blockIdx.x] = wsum[0] + wsum[1] + wsum[2] + wsum[3];
}

__global__ void finish_kernel(const double* __restrict__ partials, int nblk,
                              const float* __restrict__ betap,
                              float* __restrict__ out, int n_events) {
    double v = 0.0;
    for (int i = threadIdx.x; i < nblk; i += NTHR) v += partials[i];
    #pragma unroll
    for (int off = 32; off > 0; off >>= 1) v += __shfl_down(v, off, 64);
    __shared__ double wsum[4];
    if ((threadIdx.x & 63) == 0) wsum[threadIdx.x >> 6] = v;
    __syncthreads();
    if (threadIdx.x == 0)
        out[0] = (float)((double)n_events * (double)betap[0] -
                         (wsum[0] + wsum[1] + wsum[2] + wsum[3]));
}

extern "C" void kernel_launch(void* const* d_in, const int* in_sizes, int n_in,
                              void* d_out, int out_size, void* d_ws, size_t ws_size,
                              hipStream_t stream) {
    const int2*  idx  = (const int2*)d_in[0];
    const float* t    = (const float*)d_in[1];
    const float* t0   = (const float*)d_in[2];
    const float* tn   = (const float*)d_in[3];
    const float* z0   = (const float*)d_in[4];
    const float* v0   = (const float*)d_in[5];
    const float* beta = (const float*)d_in[6];
    const int n_events = in_sizes[1];
    const int n_pts    = in_sizes[4] / 2;

    char* base = (char*)d_ws;
    double* partials = (double*)base;
    float* xs  = (float*)(base + 32768);
    float* ys  = (float*)(base + 32768 + PTS_PAD);
    float* vxs = (float*)(base + 32768 + 2 * PTS_PAD);
    float* vys = (float*)(base + 32768 + 3 * PTS_PAD);
    float4* pts = (float4*)(base + 32768 + 4 * PTS_PAD);

    const int n_rows = n_pts - 1;
    int nblk = (n_rows + 1) / 2;          // 2500 for n_pts=5000
    if (nblk < 1) nblk = 1;
    if (nblk > MAXBLK) nblk = MAXBLK;

    pack_kernel<<<(n_pts + NTHR - 1) / NTHR, NTHR, 0, stream>>>(
        z0, v0, xs, ys, vxs, vys, pts, n_pts);
    cvm_main_kernel<<<nblk, NTHR, 0, stream>>>(idx, t, xs, ys, vxs, vys, pts,
                                               t0, tn, beta, n_events, n_pts,
                                               partials);
    finish_kernel<<<1, NTHR, 0, stream>>>(partials, nblk, beta,
                                          (float*)d_out, n_events);
}